// Round 9
// baseline (222.371 us; speedup 1.0000x reference)
//
#include <hip/hip_runtime.h>
#include <hip/hip_bf16.h>
#include <stdint.h>

#define B_   4
#define S_   2048
#define DIN  1024
#define EMB  1024
#define H_   16
#define HD_  64
#define TOK  (B_*S_)            // 8192
#define NQKV 3072

using bf16  = __hip_bfloat16;
using f32x4 = __attribute__((ext_vector_type(4))) float;
using f32x16 = __attribute__((ext_vector_type(16))) float;
using s16x8 = __attribute__((ext_vector_type(8))) short;
using bf16x8 = __attribute__((ext_vector_type(8))) __bf16;

__device__ __forceinline__ f32x4 mfma16(s16x8 a, s16x8 b, f32x4 c) {
  return __builtin_amdgcn_mfma_f32_16x16x32_bf16(
      __builtin_bit_cast(bf16x8, a), __builtin_bit_cast(bf16x8, b), c, 0, 0, 0);
}
__device__ __forceinline__ f32x16 mfma32(s16x8 a, s16x8 b, f32x16 c) {
  return __builtin_amdgcn_mfma_f32_32x32x16_bf16(
      __builtin_bit_cast(bf16x8, a), __builtin_bit_cast(bf16x8, b), c, 0, 0, 0);
}

__device__ __forceinline__ void gload_lds16(const void* g, void* l) {
  __builtin_amdgcn_global_load_lds(
      (const __attribute__((address_space(1))) uint32_t*)g,
      (__attribute__((address_space(3))) uint32_t*)l, 16, 0, 0);
}

// pack two f32 -> one u32 of 2 bf16 (lo,hi)
__device__ __forceinline__ uint32_t cvtpk_bf16(float lo, float hi) {
  uint32_t r;
  asm("v_cvt_pk_bf16_f32 %0, %1, %2" : "=v"(r) : "v"(lo), "v"(hi));
  return r;
}
// exchange a's lanes 32-63 with b's lanes 0-31
__device__ __forceinline__ void plswap32(uint32_t &a, uint32_t &b) {
  asm("v_permlane32_swap_b32 %0, %1" : "+v"(a), "+v"(b));
}

union U8 { s16x8 v; bf16 b[8]; };
union PaU { uint32_t w[4]; s16x8 v; };

// ---------------------------------------------------------------- f32 -> bf16
// Merged: one kernel converts x (4096 blocks), W_qkv (1536), W_out (512).
__global__ __launch_bounds__(256) void cvt_all(const float* __restrict__ x,
                                               const float* __restrict__ wqkv,
                                               const float* __restrict__ wout,
                                               bf16* __restrict__ xb,
                                               bf16* __restrict__ wqkvb,
                                               bf16* __restrict__ woutb) {
  int b = blockIdx.x;
  const float* in; bf16* out; int base;
  if (b < 4096)      { in = x;    out = xb;    base = b; }
  else if (b < 5632) { in = wqkv; out = wqkvb; base = b - 4096; }
  else               { in = wout; out = woutb; base = b - 5632; }
  int i = (base * 256 + (int)threadIdx.x) * 8;
  float4 a = *(const float4*)(in + i);
  float4 c = *(const float4*)(in + i + 4);
  U8 u;
  u.b[0] = __float2bfloat16(a.x); u.b[1] = __float2bfloat16(a.y);
  u.b[2] = __float2bfloat16(a.z); u.b[3] = __float2bfloat16(a.w);
  u.b[4] = __float2bfloat16(c.x); u.b[5] = __float2bfloat16(c.y);
  u.b[6] = __float2bfloat16(c.z); u.b[7] = __float2bfloat16(c.w);
  *(s16x8*)(out + i) = u.v;
}

// ---------------------------------------------------------------- GEMM (TN)
// (unchanged — passed rounds 3-8)
template<int MODE>
__global__ __launch_bounds__(256) void gemm_bt(
    const bf16* __restrict__ A, const bf16* __restrict__ Bw,
    const float* __restrict__ bias,
    bf16* __restrict__ outQK, bf16* __restrict__ outV,
    float* __restrict__ outF, int N, int K)
{
  const int tid  = threadIdx.x;
  const int lane = tid & 63;
  const int w    = tid >> 6;
  const int wm   = w >> 1, wn = w & 1;
  const int bn0  = blockIdx.x * 128;
  const int bm0  = blockIdx.y * 128;

  __shared__ __align__(16) bf16 As[128 * 64];
  __shared__ __align__(16) bf16 Bs[128 * 64];

  f32x4 acc[4][4];
  const f32x4 zero = {0.f, 0.f, 0.f, 0.f};
  for (int mt = 0; mt < 4; ++mt)
    for (int nt = 0; nt < 4; ++nt) acc[mt][nt] = zero;

  for (int kt = 0; kt < K; kt += 64) {
    for (int i = 0; i < 4; ++i) {
      int c   = i * 256 + tid;
      int row = c >> 3, p = c & 7;
      int sc  = p ^ (row & 7);
      gload_lds16(A + (size_t)(bm0 + row) * K + kt + sc * 8, (char*)As + c * 16);
      gload_lds16(Bw + (size_t)(bn0 + row) * K + kt + sc * 8, (char*)Bs + c * 16);
    }
    __syncthreads();

    s16x8 af[4][2], bfr[4][2];
    for (int mt = 0; mt < 4; ++mt)
      for (int kk = 0; kk < 2; ++kk) {
        int row  = wm * 64 + mt * 16 + (lane & 15);
        int byte = row * 128 + (((kk * 4 + (lane >> 4)) ^ (row & 7)) << 4);
        af[mt][kk] = *(const s16x8*)((const char*)As + byte);
      }
    for (int nt = 0; nt < 4; ++nt)
      for (int kk = 0; kk < 2; ++kk) {
        int row  = wn * 64 + nt * 16 + (lane & 15);
        int byte = row * 128 + (((kk * 4 + (lane >> 4)) ^ (row & 7)) << 4);
        bfr[nt][kk] = *(const s16x8*)((const char*)Bs + byte);
      }
    for (int kk = 0; kk < 2; ++kk)
      for (int mt = 0; mt < 4; ++mt)
        for (int nt = 0; nt < 4; ++nt)
          acc[mt][nt] = mfma16(af[mt][kk], bfr[nt][kk], acc[mt][nt]);
    __syncthreads();
  }

  const int col_l = lane & 15;
  const int rgrp  = lane >> 4;
  for (int mt = 0; mt < 4; ++mt)
    for (int nt = 0; nt < 4; ++nt) {
      int n0  = bn0 + wn * 64 + nt * 16;
      int col = n0 + col_l;
      float bv = bias[col];
      if (MODE == 0) {
        int h = col / 192, rem = col % 192;
        int cc = rem / 64, d = rem % 64;
        for (int r = 0; r < 4; ++r) {
          int row = bm0 + wm * 64 + mt * 16 + rgrp * 4 + r;
          bf16 bvv = __float2bfloat16(acc[mt][nt][r] + bv);
          if (cc == 2) {
            int bb = row >> 11, s = row & 2047;
            outV[(((size_t)bb * H_ + h) * HD_ + d) * S_ + s] = bvv;   // V^T
          } else {
            outQK[(size_t)row * NQKV + col] = bvv;
          }
        }
      } else {
        for (int r = 0; r < 4; ++r) {
          int row = bm0 + wm * 64 + mt * 16 + rgrp * 4 + r;
          outF[(size_t)row * EMB + col] = acc[mt][nt][r] + bv;
        }
      }
    }
}

// ---------------------------------------------------------------- attention v6
// = v5 (R8, 108 µs) with K-BLOCK-MAJOR LDS tiles instead of row-major+XOR.
// R8 counters: LDS pipe ~55 µs (41 read + 13.6 conflict) was the TOP pipe;
// conflicts = 4 cyc/ds_read_b128, structural for row-major (in each 16-lane
// quarter-wave, rows r and r+8 share a chunk column -> same 4 banks).
// Fix: Ks = [k8][kv][8 bf16], Vts = [kv8][d][8 bf16]. Fragment reads become
// base + ks*2048 + hi*1024 + row*16: each quarter-wave reads 256 CONTIGUOUS
// bytes -> zero bank conflicts (m97 pattern), and all XOR addressing VALU
// disappears. global_load_lds: LDS dest stays linear in chunk id (required,
// wave-uniform base + lane*16); only the per-lane GLOBAL source mapping
// changes (allowed). Source becomes 6KB/4KB-strided, but K/V tiles are
// L2-resident (XCD-pinned via T1), so L2 absorbs it.
__global__ __launch_bounds__(512, 2) void attn2(const bf16* __restrict__ qkvb,
                                                const bf16* __restrict__ vb,
                                                bf16* __restrict__ ob)
{
  const int tid = threadIdx.x, lane = tid & 63, w = tid >> 6;  // w 0..7
  const int hi = lane >> 5, l31 = lane & 31;
  const int f  = blockIdx.x;                       // 0..511
  const int bh = (f & 7) | (((f >> 6) & 7) << 3);  // XCD = f&7 pins bh to one XCD
  const int qt = (f >> 3) & 7;
  const int bb = bh >> 4, h = bh & 15;
  const int q0 = qt * 256;
  const size_t tokbase = (size_t)bb * S_;

  __shared__ __align__(16) bf16 Ks[2][64 * 64];    // [k8][kv][8]
  __shared__ __align__(16) bf16 Vts[2][64 * 64];   // [kv8][d][8]

  // Q fragments (B-operand: col=l31=q, k=16*ks+8*hi+e), scaled 0.125*log2e
  s16x8 qf[4];
  {
    const int qrow = q0 + w * 32 + l31;
    const bf16* qp = qkvb + (tokbase + qrow) * NQKV + h * 192 + hi * 8;
    #pragma unroll
    for (int ks = 0; ks < 4; ++ks) {
      U8 u; u.v = *(const s16x8*)(qp + ks * 16);
      #pragma unroll
      for (int j = 0; j < 8; ++j)
        u.b[j] = __float2bfloat16(__bfloat162float(u.b[j]) * 0.18033688011112042f);
      qf[ks] = u.v;
    }
  }

  f32x16 zero16;
  #pragma unroll
  for (int i = 0; i < 16; ++i) zero16[i] = 0.f;
  f32x16 oA = zero16, oB = zero16;   // C-layout: col=d(=l31/+32), row=q pattern
  f32x16 nm16 = zero16;              // all elems = -m (m starts at 0)
  float l0 = 0.f;

  const bf16* Kbase = qkvb + tokbase * NQKV + h * 192 + 64;
  const bf16* Vbase = vb + (size_t)bh * HD_ * S_;

  auto STAGE = [&](int b, int t) {
    const int kv0 = t * 64;
    const int c = tid;                       // 512 thr = 512 chunks per array
    const int k8 = c >> 6, kv = c & 63;      // K chunk (k8, kv)
    gload_lds16(Kbase + (size_t)(kv0 + kv) * NQKV + k8 * 8,
                (char*)Ks[b] + c * 16);
    const int ch = c >> 6, d = c & 63;       // V chunk (kv8, d)
    gload_lds16(Vbase + (size_t)d * S_ + kv0 + ch * 8,
                (char*)Vts[b] + c * 16);
  };

  STAGE(0, 0);
  __syncthreads();

  int cur = 0;
  for (int t = 0; t < S_ / 64; ++t) {
    if (t < S_ / 64 - 1) STAGE(cur ^ 1, t + 1);   // issue-early

    // ---- S^T - m = K · Q^T + (-m)   (lane: q=l31; kv in-register)
    f32x16 pA, pB;
    #pragma unroll
    for (int ks = 0; ks < 4; ++ks) {
      const char* kb = (const char*)Ks[cur] + (2 * ks + hi) * 1024;
      {
        s16x8 kf = *(const s16x8*)(kb + l31 * 16);
        pA = mfma32(kf, qf[ks], ks == 0 ? nm16 : pA);
      }
      {
        s16x8 kf = *(const s16x8*)(kb + 512 + l31 * 16);
        pB = mfma32(kf, qf[ks], ks == 0 ? nm16 : pB);
      }
    }

    // ---- row max of (S-m): in-lane tree + partner combine
    float mx8[8];
    #pragma unroll
    for (int i = 0; i < 8; ++i)
      mx8[i] = fmaxf(fmaxf(pA[i], pA[i + 8]), fmaxf(pB[i], pB[i + 8]));
    float pmax = fmaxf(fmaxf(fmaxf(mx8[0], mx8[4]), fmaxf(mx8[1], mx8[5])),
                       fmaxf(fmaxf(mx8[2], mx8[6]), fmaxf(mx8[3], mx8[7])));
    pmax = fmaxf(pmax, __shfl_xor(pmax, 32));

    // ---- defer-max rescale (rare); everything already in S-m domain
    if (__any(pmax > 11.0f)) {
      float al = __builtin_amdgcn_exp2f(-pmax);
      l0 *= al;
      #pragma unroll
      for (int r = 0; r < 16; ++r) {
        float alr = __shfl(al, (r & 3) + 8 * (r >> 2) + 4 * hi);
        oA[r] *= alr; oB[r] *= alr;
      }
      #pragma unroll
      for (int r = 0; r < 16; ++r) { pA[r] -= pmax; pB[r] -= pmax; }
      #pragma unroll
      for (int i = 0; i < 16; ++i) nm16[i] -= pmax;
    }

    // ---- exp2 (args <= 11 guaranteed) + partial row-sum
    #pragma unroll
    for (int r = 0; r < 16; ++r) {
      pA[r] = __builtin_amdgcn_exp2f(pA[r]);
      pB[r] = __builtin_amdgcn_exp2f(pB[r]);
    }
    float s8[8];
    #pragma unroll
    for (int i = 0; i < 8; ++i)
      s8[i] = (pA[i] + pA[i + 8]) + (pB[i] + pB[i + 8]);
    l0 += ((s8[0] + s8[1]) + (s8[2] + s8[3])) +
          ((s8[4] + s8[5]) + (s8[6] + s8[7]));

    // ---- pack P (cvt_pk + permlane32_swap) and PV per 16-kv step
    #pragma unroll
    for (int s = 0; s < 4; ++s) {
      const int sub = s & 1;
      const f32x16 &ph = (s < 2) ? pA : pB;
      uint32_t L0 = cvtpk_bf16(ph[8 * sub + 0], ph[8 * sub + 1]);
      uint32_t L1 = cvtpk_bf16(ph[8 * sub + 2], ph[8 * sub + 3]);
      uint32_t H0 = cvtpk_bf16(ph[8 * sub + 4], ph[8 * sub + 5]);
      uint32_t H1 = cvtpk_bf16(ph[8 * sub + 6], ph[8 * sub + 7]);
      plswap32(L0, H0);
      plswap32(L1, H1);
      PaU pa; pa.w[0] = L0; pa.w[1] = L1; pa.w[2] = H0; pa.w[3] = H1;
      const char* vbp = (const char*)Vts[cur] + (2 * s + hi) * 1024;
      {
        s16x8 vf = *(const s16x8*)(vbp + l31 * 16);
        oA = mfma32(pa.v, vf, oA);
      }
      {
        s16x8 vf = *(const s16x8*)(vbp + 512 + l31 * 16);
        oB = mfma32(pa.v, vf, oB);
      }
    }
    __syncthreads();   // one vmcnt(0)+barrier per tile
    cur ^= 1;
  }

  // ---- epilogue: combine partner l0, normalize, write
  float l0t = l0 + __shfl_xor(l0, 32);
  float inv = 1.0f / l0t;                  // lane's q = l31
  #pragma unroll
  for (int r = 0; r < 16; ++r) {
    int q = (r & 3) + 8 * (r >> 2) + 4 * hi;
    float invr = __shfl(inv, q);
    int qrow = q0 + w * 32 + q;
    bf16* op = ob + (tokbase + qrow) * EMB + h * 64 + l31;
    op[0]  = __float2bfloat16(oA[r] * invr);
    op[32] = __float2bfloat16(oB[r] * invr);
  }
}

// ---------------------------------------------------------------- launcher
// Workspace map (ob aliases xb — xb dead after gemm0, rewritten every replay):
//   [0,16MB) xb->ob  [16,22) wqkvb  [22,24) woutb  [24,72) qkvb  [72,88) vb
extern "C" void kernel_launch(void* const* d_in, const int* in_sizes, int n_in,
                              void* d_out, int out_size, void* d_ws, size_t ws_size,
                              hipStream_t stream) {
  const float* x    = (const float*)d_in[0];
  const float* Wqkv = (const float*)d_in[1];
  const float* bqkv = (const float*)d_in[2];
  const float* Wout = (const float*)d_in[3];
  const float* bout = (const float*)d_in[4];
  float* out = (float*)d_out;

  char* ws = (char*)d_ws;
  bf16* xb    = (bf16*)(ws);
  bf16* wqkvb = (bf16*)(ws + 16777216);
  bf16* woutb = (bf16*)(ws + 23068672);
  bf16* qkvb  = (bf16*)(ws + 25165824);
  bf16* vb    = (bf16*)(ws + 75497472);
  bf16* ob    = xb;

  cvt_all<<<dim3(6144), 256, 0, stream>>>(x, Wqkv, Wout, xb, wqkvb, woutb);

  gemm_bt<0><<<dim3(NQKV / 128, TOK / 128), 256, 0, stream>>>(
      xb, wqkvb, bqkv, qkvb, vb, nullptr, NQKV, DIN);

  attn2<<<dim3(512), 512, 0, stream>>>(qkvb, vb, ob);

  gemm_bt<1><<<dim3(EMB / 128, TOK / 128), 256, 0, stream>>>(
      ob, woutb, bout, nullptr, nullptr, out, EMB, EMB);
}

// Round 10
// 204.252 us; speedup vs baseline: 1.0887x; 1.0887x over previous
//
#include <hip/hip_runtime.h>
#include <hip/hip_bf16.h>
#include <stdint.h>

#define B_   4
#define S_   2048
#define DIN  1024
#define EMB  1024
#define H_   16
#define HD_  64
#define TOK  (B_*S_)            // 8192
#define NQKV 3072

using bf16  = __hip_bfloat16;
using f32x4 = __attribute__((ext_vector_type(4))) float;
using f32x16 = __attribute__((ext_vector_type(16))) float;
using s16x8 = __attribute__((ext_vector_type(8))) short;
using bf16x8 = __attribute__((ext_vector_type(8))) __bf16;

__device__ __forceinline__ f32x4 mfma16(s16x8 a, s16x8 b, f32x4 c) {
  return __builtin_amdgcn_mfma_f32_16x16x32_bf16(
      __builtin_bit_cast(bf16x8, a), __builtin_bit_cast(bf16x8, b), c, 0, 0, 0);
}
__device__ __forceinline__ f32x16 mfma32(s16x8 a, s16x8 b, f32x16 c) {
  return __builtin_amdgcn_mfma_f32_32x32x16_bf16(
      __builtin_bit_cast(bf16x8, a), __builtin_bit_cast(bf16x8, b), c, 0, 0, 0);
}

__device__ __forceinline__ void gload_lds16(const void* g, void* l) {
  __builtin_amdgcn_global_load_lds(
      (const __attribute__((address_space(1))) uint32_t*)g,
      (__attribute__((address_space(3))) uint32_t*)l, 16, 0, 0);
}

// pack two f32 -> one u32 of 2 bf16 (lo,hi)
__device__ __forceinline__ uint32_t cvtpk_bf16(float lo, float hi) {
  uint32_t r;
  asm("v_cvt_pk_bf16_f32 %0, %1, %2" : "=v"(r) : "v"(lo), "v"(hi));
  return r;
}
// exchange a's lanes 32-63 with b's lanes 0-31
__device__ __forceinline__ void plswap32(uint32_t &a, uint32_t &b) {
  asm("v_permlane32_swap_b32 %0, %1" : "+v"(a), "+v"(b));
}

union U8 { s16x8 v; bf16 b[8]; };
union PaU { uint32_t w[4]; s16x8 v; };

// ---------------------------------------------------------------- f32 -> bf16
// Merged: one kernel converts x (4096 blocks), W_qkv (1536), W_out (512).
__global__ __launch_bounds__(256) void cvt_all(const float* __restrict__ x,
                                               const float* __restrict__ wqkv,
                                               const float* __restrict__ wout,
                                               bf16* __restrict__ xb,
                                               bf16* __restrict__ wqkvb,
                                               bf16* __restrict__ woutb) {
  int b = blockIdx.x;
  const float* in; bf16* out; int base;
  if (b < 4096)      { in = x;    out = xb;    base = b; }
  else if (b < 5632) { in = wqkv; out = wqkvb; base = b - 4096; }
  else               { in = wout; out = woutb; base = b - 5632; }
  int i = (base * 256 + (int)threadIdx.x) * 8;
  float4 a = *(const float4*)(in + i);
  float4 c = *(const float4*)(in + i + 4);
  U8 u;
  u.b[0] = __float2bfloat16(a.x); u.b[1] = __float2bfloat16(a.y);
  u.b[2] = __float2bfloat16(a.z); u.b[3] = __float2bfloat16(a.w);
  u.b[4] = __float2bfloat16(c.x); u.b[5] = __float2bfloat16(c.y);
  u.b[6] = __float2bfloat16(c.z); u.b[7] = __float2bfloat16(c.w);
  *(s16x8*)(out + i) = u.v;
}

// ---------------------------------------------------------------- GEMM (TN)
// (unchanged — passed rounds 3-9)
template<int MODE>
__global__ __launch_bounds__(256) void gemm_bt(
    const bf16* __restrict__ A, const bf16* __restrict__ Bw,
    const float* __restrict__ bias,
    bf16* __restrict__ outQK, bf16* __restrict__ outV,
    float* __restrict__ outF, int N, int K)
{
  const int tid  = threadIdx.x;
  const int lane = tid & 63;
  const int w    = tid >> 6;
  const int wm   = w >> 1, wn = w & 1;
  const int bn0  = blockIdx.x * 128;
  const int bm0  = blockIdx.y * 128;

  __shared__ __align__(16) bf16 As[128 * 64];
  __shared__ __align__(16) bf16 Bs[128 * 64];

  f32x4 acc[4][4];
  const f32x4 zero = {0.f, 0.f, 0.f, 0.f};
  for (int mt = 0; mt < 4; ++mt)
    for (int nt = 0; nt < 4; ++nt) acc[mt][nt] = zero;

  for (int kt = 0; kt < K; kt += 64) {
    for (int i = 0; i < 4; ++i) {
      int c   = i * 256 + tid;
      int row = c >> 3, p = c & 7;
      int sc  = p ^ (row & 7);
      gload_lds16(A + (size_t)(bm0 + row) * K + kt + sc * 8, (char*)As + c * 16);
      gload_lds16(Bw + (size_t)(bn0 + row) * K + kt + sc * 8, (char*)Bs + c * 16);
    }
    __syncthreads();

    s16x8 af[4][2], bfr[4][2];
    for (int mt = 0; mt < 4; ++mt)
      for (int kk = 0; kk < 2; ++kk) {
        int row  = wm * 64 + mt * 16 + (lane & 15);
        int byte = row * 128 + (((kk * 4 + (lane >> 4)) ^ (row & 7)) << 4);
        af[mt][kk] = *(const s16x8*)((const char*)As + byte);
      }
    for (int nt = 0; nt < 4; ++nt)
      for (int kk = 0; kk < 2; ++kk) {
        int row  = wn * 64 + nt * 16 + (lane & 15);
        int byte = row * 128 + (((kk * 4 + (lane >> 4)) ^ (row & 7)) << 4);
        bfr[nt][kk] = *(const s16x8*)((const char*)Bs + byte);
      }
    for (int kk = 0; kk < 2; ++kk)
      for (int mt = 0; mt < 4; ++mt)
        for (int nt = 0; nt < 4; ++nt)
          acc[mt][nt] = mfma16(af[mt][kk], bfr[nt][kk], acc[mt][nt]);
    __syncthreads();
  }

  const int col_l = lane & 15;
  const int rgrp  = lane >> 4;
  for (int mt = 0; mt < 4; ++mt)
    for (int nt = 0; nt < 4; ++nt) {
      int n0  = bn0 + wn * 64 + nt * 16;
      int col = n0 + col_l;
      float bv = bias[col];
      if (MODE == 0) {
        int h = col / 192, rem = col % 192;
        int cc = rem / 64, d = rem % 64;
        for (int r = 0; r < 4; ++r) {
          int row = bm0 + wm * 64 + mt * 16 + rgrp * 4 + r;
          bf16 bvv = __float2bfloat16(acc[mt][nt][r] + bv);
          if (cc == 2) {
            int bb = row >> 11, s = row & 2047;
            outV[(((size_t)bb * H_ + h) * HD_ + d) * S_ + s] = bvv;   // V^T
          } else {
            outQK[(size_t)row * NQKV + col] = bvv;
          }
        }
      } else {
        for (int r = 0; r < 4; ++r) {
          int row = bm0 + wm * 64 + mt * 16 + rgrp * 4 + r;
          outF[(size_t)row * EMB + col] = acc[mt][nt][r] + bv;
        }
      }
    }
}

// ---------------------------------------------------------------- attention v7
// = v6 (R9: k-block-major LDS, 0 bank conflicts) with REG-STAGING (T14) to fix
// R9's regression. R9 diagnosis: global_load_lds locks LDS layout to global
// access pattern -> k-block-major forced 64-way-scattered source (6KB/4KB
// lane stride), and the vmcnt(0)-at-barrier drain exposed ~20 µs of TA
// scatter latency. Fix: coalesced global->VGPR loads issued at tile start
// (issue-early), ds_write_b128 into k-block-major LDS AFTER the compute
// phase (write-late) — HBM/L2 latency hides under ~3 µs of compute, and the
// barrier only drains lgkmcnt. ds_write has free per-lane addressing.
// k8-block stride padded 1024->1040 B: write bank = 4(p+row)%32 -> 2-way
// (free); unpadded writes would be 8-way. Reads stay contiguous 512B per
// half-wave (R9 measured 0 conflicts).
__global__ __launch_bounds__(512, 2) void attn2(const bf16* __restrict__ qkvb,
                                                const bf16* __restrict__ vb,
                                                bf16* __restrict__ ob)
{
  const int tid = threadIdx.x, lane = tid & 63, w = tid >> 6;  // w 0..7
  const int hi = lane >> 5, l31 = lane & 31;
  const int f  = blockIdx.x;                       // 0..511
  const int bh = (f & 7) | (((f >> 6) & 7) << 3);  // XCD = f&7 pins bh to one XCD
  const int qt = (f >> 3) & 7;
  const int bb = bh >> 4, h = bh & 15;
  const int q0 = qt * 256;
  const size_t tokbase = (size_t)bb * S_;

  // k-block-major, padded: chunk (k8, r) at byte k8*1040 + r*16 (data 1024 + 16 pad)
  __shared__ __align__(16) char KsB[2][8 * 1040];   // K  [k8][kv][8 bf16]
  __shared__ __align__(16) char VtsB[2][8 * 1040];  // V^T[kv8][d][8 bf16]

  // Q fragments (B-operand: col=l31=q, k=16*ks+8*hi+e), scaled 0.125*log2e
  s16x8 qf[4];
  {
    const int qrow = q0 + w * 32 + l31;
    const bf16* qp = qkvb + (tokbase + qrow) * NQKV + h * 192 + hi * 8;
    #pragma unroll
    for (int ks = 0; ks < 4; ++ks) {
      U8 u; u.v = *(const s16x8*)(qp + ks * 16);
      #pragma unroll
      for (int j = 0; j < 8; ++j)
        u.b[j] = __float2bfloat16(__bfloat162float(u.b[j]) * 0.18033688011112042f);
      qf[ks] = u.v;
    }
  }

  f32x16 zero16;
  #pragma unroll
  for (int i = 0; i < 16; ++i) zero16[i] = 0.f;
  f32x16 oA = zero16, oB = zero16;   // C-layout: col=d(=l31/+32), row=q pattern
  f32x16 nm16 = zero16;              // all elems = -m (m starts at 0)
  float l0 = 0.f;

  const bf16* Kbase = qkvb + tokbase * NQKV + h * 192 + 64;
  const bf16* Vbase = vb + (size_t)bh * HD_ * S_;

  // staging decomposition: thread -> (row = tid>>3, p = tid&7); coalesced
  // global reads (8 threads cover one 128B row), k-block-major LDS writes.
  const int srow = tid >> 3, sp = tid & 7;
  const bf16* kSrc = Kbase + (size_t)srow * NQKV + sp * 8;       // + t*64*NQKV
  const bf16* vSrc = Vbase + (size_t)srow * S_ + sp * 8;         // + t*64
  const int   sByte = sp * 1040 + srow * 16;

  s16x8 kreg, vreg;
  auto LOAD = [&](int t) {
    kreg = *(const s16x8*)(kSrc + (size_t)t * 64 * NQKV);
    vreg = *(const s16x8*)(vSrc + (size_t)t * 64);
  };
  auto WRITE = [&](int b) {
    *(s16x8*)(KsB[b] + sByte) = kreg;
    *(s16x8*)(VtsB[b] + sByte) = vreg;
  };

  LOAD(0);
  WRITE(0);          // prologue: one exposed HBM latency
  __syncthreads();

  int cur = 0;
  for (int t = 0; t < S_ / 64; ++t) {
    if (t < S_ / 64 - 1) LOAD(t + 1);   // issue-early: hides under compute

    // ---- S^T - m = K · Q^T + (-m)   (lane: q=l31; kv in-register)
    f32x16 pA, pB;
    #pragma unroll
    for (int ks = 0; ks < 4; ++ks) {
      const char* kb = KsB[cur] + (2 * ks + hi) * 1040;
      {
        s16x8 kf = *(const s16x8*)(kb + l31 * 16);
        pA = mfma32(kf, qf[ks], ks == 0 ? nm16 : pA);
      }
      {
        s16x8 kf = *(const s16x8*)(kb + 512 + l31 * 16);
        pB = mfma32(kf, qf[ks], ks == 0 ? nm16 : pB);
      }
    }

    // ---- row max of (S-m): in-lane tree + partner combine
    float mx8[8];
    #pragma unroll
    for (int i = 0; i < 8; ++i)
      mx8[i] = fmaxf(fmaxf(pA[i], pA[i + 8]), fmaxf(pB[i], pB[i + 8]));
    float pmax = fmaxf(fmaxf(fmaxf(mx8[0], mx8[4]), fmaxf(mx8[1], mx8[5])),
                       fmaxf(fmaxf(mx8[2], mx8[6]), fmaxf(mx8[3], mx8[7])));
    pmax = fmaxf(pmax, __shfl_xor(pmax, 32));

    // ---- defer-max rescale (rare); everything already in S-m domain
    if (__any(pmax > 11.0f)) {
      float al = __builtin_amdgcn_exp2f(-pmax);
      l0 *= al;
      #pragma unroll
      for (int r = 0; r < 16; ++r) {
        float alr = __shfl(al, (r & 3) + 8 * (r >> 2) + 4 * hi);
        oA[r] *= alr; oB[r] *= alr;
      }
      #pragma unroll
      for (int r = 0; r < 16; ++r) { pA[r] -= pmax; pB[r] -= pmax; }
      #pragma unroll
      for (int i = 0; i < 16; ++i) nm16[i] -= pmax;
    }

    // ---- exp2 (args <= 11 guaranteed) + partial row-sum
    #pragma unroll
    for (int r = 0; r < 16; ++r) {
      pA[r] = __builtin_amdgcn_exp2f(pA[r]);
      pB[r] = __builtin_amdgcn_exp2f(pB[r]);
    }
    float s8[8];
    #pragma unroll
    for (int i = 0; i < 8; ++i)
      s8[i] = (pA[i] + pA[i + 8]) + (pB[i] + pB[i + 8]);
    l0 += ((s8[0] + s8[1]) + (s8[2] + s8[3])) +
          ((s8[4] + s8[5]) + (s8[6] + s8[7]));

    // ---- pack P (cvt_pk + permlane32_swap) and PV per 16-kv step
    #pragma unroll
    for (int s = 0; s < 4; ++s) {
      const int sub = s & 1;
      const f32x16 &ph = (s < 2) ? pA : pB;
      uint32_t L0 = cvtpk_bf16(ph[8 * sub + 0], ph[8 * sub + 1]);
      uint32_t L1 = cvtpk_bf16(ph[8 * sub + 2], ph[8 * sub + 3]);
      uint32_t H0 = cvtpk_bf16(ph[8 * sub + 4], ph[8 * sub + 5]);
      uint32_t H1 = cvtpk_bf16(ph[8 * sub + 6], ph[8 * sub + 7]);
      plswap32(L0, H0);
      plswap32(L1, H1);
      PaU pa; pa.w[0] = L0; pa.w[1] = L1; pa.w[2] = H0; pa.w[3] = H1;
      const char* vbp = VtsB[cur] + (2 * s + hi) * 1040;
      {
        s16x8 vf = *(const s16x8*)(vbp + l31 * 16);
        oA = mfma32(pa.v, vf, oA);
      }
      {
        s16x8 vf = *(const s16x8*)(vbp + 512 + l31 * 16);
        oB = mfma32(pa.v, vf, oB);
      }
    }

    // ---- write-late: loads landed during compute; barrier drains lgkm only
    if (t < S_ / 64 - 1) WRITE(cur ^ 1);
    __syncthreads();
    cur ^= 1;
  }

  // ---- epilogue: combine partner l0, normalize, write
  float l0t = l0 + __shfl_xor(l0, 32);
  float inv = 1.0f / l0t;                  // lane's q = l31
  #pragma unroll
  for (int r = 0; r < 16; ++r) {
    int q = (r & 3) + 8 * (r >> 2) + 4 * hi;
    float invr = __shfl(inv, q);
    int qrow = q0 + w * 32 + q;
    bf16* op = ob + (tokbase + qrow) * EMB + h * 64 + l31;
    op[0]  = __float2bfloat16(oA[r] * invr);
    op[32] = __float2bfloat16(oB[r] * invr);
  }
}

// ---------------------------------------------------------------- launcher
// Workspace map (ob aliases xb — xb dead after gemm0, rewritten every replay):
//   [0,16MB) xb->ob  [16,22) wqkvb  [22,24) woutb  [24,72) qkvb  [72,88) vb
extern "C" void kernel_launch(void* const* d_in, const int* in_sizes, int n_in,
                              void* d_out, int out_size, void* d_ws, size_t ws_size,
                              hipStream_t stream) {
  const float* x    = (const float*)d_in[0];
  const float* Wqkv = (const float*)d_in[1];
  const float* bqkv = (const float*)d_in[2];
  const float* Wout = (const float*)d_in[3];
  const float* bout = (const float*)d_in[4];
  float* out = (float*)d_out;

  char* ws = (char*)d_ws;
  bf16* xb    = (bf16*)(ws);
  bf16* wqkvb = (bf16*)(ws + 16777216);
  bf16* woutb = (bf16*)(ws + 23068672);
  bf16* qkvb  = (bf16*)(ws + 25165824);
  bf16* vb    = (bf16*)(ws + 75497472);
  bf16* ob    = xb;

  cvt_all<<<dim3(6144), 256, 0, stream>>>(x, Wqkv, Wout, xb, wqkvb, woutb);

  gemm_bt<0><<<dim3(NQKV / 128, TOK / 128), 256, 0, stream>>>(
      xb, wqkvb, bqkv, qkvb, vb, nullptr, NQKV, DIN);

  attn2<<<dim3(512), 512, 0, stream>>>(qkvb, vb, ob);

  gemm_bt<1><<<dim3(EMB / 128, TOK / 128), 256, 0, stream>>>(
      ob, woutb, bout, nullptr, nullptr, out, EMB, EMB);
}

// Round 11
// 195.889 us; speedup vs baseline: 1.1352x; 1.0427x over previous
//
#include <hip/hip_runtime.h>
#include <hip/hip_bf16.h>
#include <stdint.h>

#define B_   4
#define S_   2048
#define DIN  1024
#define EMB  1024
#define H_   16
#define HD_  64
#define TOK  (B_*S_)            // 8192
#define NQKV 3072

using bf16  = __hip_bfloat16;
using f32x4 = __attribute__((ext_vector_type(4))) float;
using f32x16 = __attribute__((ext_vector_type(16))) float;
using s16x8 = __attribute__((ext_vector_type(8))) short;
using bf16x8 = __attribute__((ext_vector_type(8))) __bf16;

__device__ __forceinline__ f32x4 mfma16(s16x8 a, s16x8 b, f32x4 c) {
  return __builtin_amdgcn_mfma_f32_16x16x32_bf16(
      __builtin_bit_cast(bf16x8, a), __builtin_bit_cast(bf16x8, b), c, 0, 0, 0);
}
__device__ __forceinline__ f32x16 mfma32(s16x8 a, s16x8 b, f32x16 c) {
  return __builtin_amdgcn_mfma_f32_32x32x16_bf16(
      __builtin_bit_cast(bf16x8, a), __builtin_bit_cast(bf16x8, b), c, 0, 0, 0);
}

__device__ __forceinline__ void gload_lds16(const void* g, void* l) {
  __builtin_amdgcn_global_load_lds(
      (const __attribute__((address_space(1))) uint32_t*)g,
      (__attribute__((address_space(3))) uint32_t*)l, 16, 0, 0);
}

// pack two f32 -> one u32 of 2 bf16 (lo,hi)
__device__ __forceinline__ uint32_t cvtpk_bf16(float lo, float hi) {
  uint32_t r;
  asm("v_cvt_pk_bf16_f32 %0, %1, %2" : "=v"(r) : "v"(lo), "v"(hi));
  return r;
}
// exchange a's lanes 32-63 with b's lanes 0-31
__device__ __forceinline__ void plswap32(uint32_t &a, uint32_t &b) {
  asm("v_permlane32_swap_b32 %0, %1" : "+v"(a), "+v"(b));
}

union U8 { s16x8 v; bf16 b[8]; };
union PaU { uint32_t w[4]; s16x8 v; };

// ---------------------------------------------------------------- f32 -> bf16
// Merged: one kernel converts x (4096 blocks), W_qkv (1536), W_out (512).
__global__ __launch_bounds__(256) void cvt_all(const float* __restrict__ x,
                                               const float* __restrict__ wqkv,
                                               const float* __restrict__ wout,
                                               bf16* __restrict__ xb,
                                               bf16* __restrict__ wqkvb,
                                               bf16* __restrict__ woutb) {
  int b = blockIdx.x;
  const float* in; bf16* out; int base;
  if (b < 4096)      { in = x;    out = xb;    base = b; }
  else if (b < 5632) { in = wqkv; out = wqkvb; base = b - 4096; }
  else               { in = wout; out = woutb; base = b - 5632; }
  int i = (base * 256 + (int)threadIdx.x) * 8;
  float4 a = *(const float4*)(in + i);
  float4 c = *(const float4*)(in + i + 4);
  U8 u;
  u.b[0] = __float2bfloat16(a.x); u.b[1] = __float2bfloat16(a.y);
  u.b[2] = __float2bfloat16(a.z); u.b[3] = __float2bfloat16(a.w);
  u.b[4] = __float2bfloat16(c.x); u.b[5] = __float2bfloat16(c.y);
  u.b[6] = __float2bfloat16(c.z); u.b[7] = __float2bfloat16(c.w);
  *(s16x8*)(out + i) = u.v;
}

// ---------------------------------------------------------------- GEMM (TN)
// (unchanged — passed rounds 3-10)
template<int MODE>
__global__ __launch_bounds__(256) void gemm_bt(
    const bf16* __restrict__ A, const bf16* __restrict__ Bw,
    const float* __restrict__ bias,
    bf16* __restrict__ outQK, bf16* __restrict__ outV,
    float* __restrict__ outF, int N, int K)
{
  const int tid  = threadIdx.x;
  const int lane = tid & 63;
  const int w    = tid >> 6;
  const int wm   = w >> 1, wn = w & 1;
  const int bn0  = blockIdx.x * 128;
  const int bm0  = blockIdx.y * 128;

  __shared__ __align__(16) bf16 As[128 * 64];
  __shared__ __align__(16) bf16 Bs[128 * 64];

  f32x4 acc[4][4];
  const f32x4 zero = {0.f, 0.f, 0.f, 0.f};
  for (int mt = 0; mt < 4; ++mt)
    for (int nt = 0; nt < 4; ++nt) acc[mt][nt] = zero;

  for (int kt = 0; kt < K; kt += 64) {
    for (int i = 0; i < 4; ++i) {
      int c   = i * 256 + tid;
      int row = c >> 3, p = c & 7;
      int sc  = p ^ (row & 7);
      gload_lds16(A + (size_t)(bm0 + row) * K + kt + sc * 8, (char*)As + c * 16);
      gload_lds16(Bw + (size_t)(bn0 + row) * K + kt + sc * 8, (char*)Bs + c * 16);
    }
    __syncthreads();

    s16x8 af[4][2], bfr[4][2];
    for (int mt = 0; mt < 4; ++mt)
      for (int kk = 0; kk < 2; ++kk) {
        int row  = wm * 64 + mt * 16 + (lane & 15);
        int byte = row * 128 + (((kk * 4 + (lane >> 4)) ^ (row & 7)) << 4);
        af[mt][kk] = *(const s16x8*)((const char*)As + byte);
      }
    for (int nt = 0; nt < 4; ++nt)
      for (int kk = 0; kk < 2; ++kk) {
        int row  = wn * 64 + nt * 16 + (lane & 15);
        int byte = row * 128 + (((kk * 4 + (lane >> 4)) ^ (row & 7)) << 4);
        bfr[nt][kk] = *(const s16x8*)((const char*)Bs + byte);
      }
    for (int kk = 0; kk < 2; ++kk)
      for (int mt = 0; mt < 4; ++mt)
        for (int nt = 0; nt < 4; ++nt)
          acc[mt][nt] = mfma16(af[mt][kk], bfr[nt][kk], acc[mt][nt]);
    __syncthreads();
  }

  const int col_l = lane & 15;
  const int rgrp  = lane >> 4;
  for (int mt = 0; mt < 4; ++mt)
    for (int nt = 0; nt < 4; ++nt) {
      int n0  = bn0 + wn * 64 + nt * 16;
      int col = n0 + col_l;
      float bv = bias[col];
      if (MODE == 0) {
        int h = col / 192, rem = col % 192;
        int cc = rem / 64, d = rem % 64;
        for (int r = 0; r < 4; ++r) {
          int row = bm0 + wm * 64 + mt * 16 + rgrp * 4 + r;
          bf16 bvv = __float2bfloat16(acc[mt][nt][r] + bv);
          if (cc == 2) {
            int bb = row >> 11, s = row & 2047;
            outV[(((size_t)bb * H_ + h) * HD_ + d) * S_ + s] = bvv;   // V^T
          } else {
            outQK[(size_t)row * NQKV + col] = bvv;
          }
        }
      } else {
        for (int r = 0; r < 4; ++r) {
          int row = bm0 + wm * 64 + mt * 16 + rgrp * 4 + r;
          outF[(size_t)row * EMB + col] = acc[mt][nt][r] + bv;
        }
      }
    }
}

// ---------------------------------------------------------------- attention v8
// = v7 (R10: k-block-major LDS + reg-staging, 95.5 µs) with 64 Q-ROWS PER WAVE
// (two Q-groups g0/g1). Key lever: each K/V fragment ds_read now feeds 2x the
// MFMA work -> per-CU LDS reads halve (R10 decomposition: LDS ~46 µs was
// co-critical with VALU ~46). Grid 256 = exactly 1 block/CU (perfect balance,
// K/V staged once per 512 q-rows -> FETCH halves). VALU & MFMA totals
// unchanged. Cost: ~2x live state (qf/o/nm/l0 per group, 4 P-chains
// transiently) -> peak ~220 VGPR. __launch_bounds__(512,1): cap >= 256 under
// either arg2 semantics (R7 lesson). Spill watch: VGPR=256 + FETCH/WRITE
// blowup => revert.
__global__ __launch_bounds__(512, 1) void attn2(const bf16* __restrict__ qkvb,
                                                const bf16* __restrict__ vb,
                                                bf16* __restrict__ ob)
{
  const int tid = threadIdx.x, lane = tid & 63, w = tid >> 6;  // w 0..7
  const int hi = lane >> 5, l31 = lane & 31;
  const int f  = blockIdx.x;                       // 0..255
  const int bh = (f & 7) | ((f >> 5) << 3);        // XCD = f&7 pins bh to one XCD
  const int qt = (f >> 3) & 3;
  const int bb = bh >> 4, h = bh & 15;
  const int q0 = qt * 512;
  const size_t tokbase = (size_t)bb * S_;

  // k-block-major, padded: chunk (k8, r) at byte k8*1040 + r*16
  __shared__ __align__(16) char KsB[2][8 * 1040];   // K  [k8][kv][8 bf16]
  __shared__ __align__(16) char VtsB[2][8 * 1040];  // V^T[kv8][d][8 bf16]

  // Q fragments for both groups (B-operand: col=l31=q, k=16*ks+8*hi+e),
  // scaled 0.125*log2e
  s16x8 qf0[4], qf1[4];
  {
    const int qrow = q0 + w * 64 + l31;
    const bf16* qp = qkvb + (tokbase + qrow) * NQKV + h * 192 + hi * 8;
    #pragma unroll
    for (int ks = 0; ks < 4; ++ks) {
      U8 u; u.v = *(const s16x8*)(qp + ks * 16);
      #pragma unroll
      for (int j = 0; j < 8; ++j)
        u.b[j] = __float2bfloat16(__bfloat162float(u.b[j]) * 0.18033688011112042f);
      qf0[ks] = u.v;
    }
    const bf16* qp1 = qp + (size_t)32 * NQKV;
    #pragma unroll
    for (int ks = 0; ks < 4; ++ks) {
      U8 u; u.v = *(const s16x8*)(qp1 + ks * 16);
      #pragma unroll
      for (int j = 0; j < 8; ++j)
        u.b[j] = __float2bfloat16(__bfloat162float(u.b[j]) * 0.18033688011112042f);
      qf1[ks] = u.v;
    }
  }

  f32x16 zero16;
  #pragma unroll
  for (int i = 0; i < 16; ++i) zero16[i] = 0.f;
  f32x16 oA0 = zero16, oB0 = zero16, oA1 = zero16, oB1 = zero16;
  f32x16 nm0 = zero16, nm1 = zero16;   // all elems = -m_g (m starts at 0)
  float l00 = 0.f, l01 = 0.f;

  const bf16* Kbase = qkvb + tokbase * NQKV + h * 192 + 64;
  const bf16* Vbase = vb + (size_t)bh * HD_ * S_;

  // staging: thread -> (row = tid>>3, p = tid&7); coalesced global reads,
  // k-block-major LDS writes (write-late).
  const int srow = tid >> 3, sp = tid & 7;
  const bf16* kSrc = Kbase + (size_t)srow * NQKV + sp * 8;
  const bf16* vSrc = Vbase + (size_t)srow * S_ + sp * 8;
  const int   sByte = sp * 1040 + srow * 16;

  s16x8 kreg, vreg;
  auto LOAD = [&](int t) {
    kreg = *(const s16x8*)(kSrc + (size_t)t * 64 * NQKV);
    vreg = *(const s16x8*)(vSrc + (size_t)t * 64);
  };
  auto WRITE = [&](int b) {
    *(s16x8*)(KsB[b] + sByte) = kreg;
    *(s16x8*)(VtsB[b] + sByte) = vreg;
  };

  LOAD(0);
  WRITE(0);
  __syncthreads();

  int cur = 0;
  for (int t = 0; t < S_ / 64; ++t) {
    if (t < S_ / 64 - 1) LOAD(t + 1);   // issue-early

    // ---- S^T - m = K · Q^T + (-m) for both q-groups; K-frags reused
    f32x16 pA0, pB0, pA1, pB1;
    #pragma unroll
    for (int ks = 0; ks < 4; ++ks) {
      const char* kb = KsB[cur] + (2 * ks + hi) * 1040;
      s16x8 klo = *(const s16x8*)(kb + l31 * 16);
      s16x8 khi = *(const s16x8*)(kb + 512 + l31 * 16);
      pA0 = mfma32(klo, qf0[ks], ks == 0 ? nm0 : pA0);
      pB0 = mfma32(khi, qf0[ks], ks == 0 ? nm0 : pB0);
      pA1 = mfma32(klo, qf1[ks], ks == 0 ? nm1 : pA1);
      pB1 = mfma32(khi, qf1[ks], ks == 0 ? nm1 : pB1);
    }

    // ---- row maxes (in-lane tree + partner combine), per group
    float mx0[8], mx1[8];
    #pragma unroll
    for (int i = 0; i < 8; ++i) {
      mx0[i] = fmaxf(fmaxf(pA0[i], pA0[i + 8]), fmaxf(pB0[i], pB0[i + 8]));
      mx1[i] = fmaxf(fmaxf(pA1[i], pA1[i + 8]), fmaxf(pB1[i], pB1[i + 8]));
    }
    float pmax0 = fmaxf(fmaxf(fmaxf(mx0[0], mx0[4]), fmaxf(mx0[1], mx0[5])),
                        fmaxf(fmaxf(mx0[2], mx0[6]), fmaxf(mx0[3], mx0[7])));
    float pmax1 = fmaxf(fmaxf(fmaxf(mx1[0], mx1[4]), fmaxf(mx1[1], mx1[5])),
                        fmaxf(fmaxf(mx1[2], mx1[6]), fmaxf(mx1[3], mx1[7])));
    pmax0 = fmaxf(pmax0, __shfl_xor(pmax0, 32));
    pmax1 = fmaxf(pmax1, __shfl_xor(pmax1, 32));

    // ---- defer-max rescale (rare); merged check, per-group shift
    if (__any(fmaxf(pmax0, pmax1) > 11.0f)) {
      float al0 = __builtin_amdgcn_exp2f(-pmax0);
      float al1 = __builtin_amdgcn_exp2f(-pmax1);
      l00 *= al0; l01 *= al1;
      #pragma unroll
      for (int r = 0; r < 16; ++r) {
        int crow = (r & 3) + 8 * (r >> 2) + 4 * hi;
        float a0 = __shfl(al0, crow), a1 = __shfl(al1, crow);
        oA0[r] *= a0; oB0[r] *= a0;
        oA1[r] *= a1; oB1[r] *= a1;
      }
      #pragma unroll
      for (int r = 0; r < 16; ++r) {
        pA0[r] -= pmax0; pB0[r] -= pmax0;
        pA1[r] -= pmax1; pB1[r] -= pmax1;
      }
      #pragma unroll
      for (int i = 0; i < 16; ++i) { nm0[i] -= pmax0; nm1[i] -= pmax1; }
    }

    // ---- exp2 (args <= 11) + partial row-sums
    #pragma unroll
    for (int r = 0; r < 16; ++r) {
      pA0[r] = __builtin_amdgcn_exp2f(pA0[r]);
      pB0[r] = __builtin_amdgcn_exp2f(pB0[r]);
      pA1[r] = __builtin_amdgcn_exp2f(pA1[r]);
      pB1[r] = __builtin_amdgcn_exp2f(pB1[r]);
    }
    {
      float s80[8], s81[8];
      #pragma unroll
      for (int i = 0; i < 8; ++i) {
        s80[i] = (pA0[i] + pA0[i + 8]) + (pB0[i] + pB0[i + 8]);
        s81[i] = (pA1[i] + pA1[i + 8]) + (pB1[i] + pB1[i + 8]);
      }
      l00 += ((s80[0] + s80[1]) + (s80[2] + s80[3])) +
             ((s80[4] + s80[5]) + (s80[6] + s80[7]));
      l01 += ((s81[0] + s81[1]) + (s81[2] + s81[3])) +
             ((s81[4] + s81[5]) + (s81[6] + s81[7]));
    }

    // ---- pack P (cvt_pk + permlane32_swap) for both groups
    PaU pa0[4], pa1[4];
    #pragma unroll
    for (int s = 0; s < 4; ++s) {
      const int sub = s & 1;
      {
        const f32x16 &ph = (s < 2) ? pA0 : pB0;
        uint32_t L0 = cvtpk_bf16(ph[8 * sub + 0], ph[8 * sub + 1]);
        uint32_t L1 = cvtpk_bf16(ph[8 * sub + 2], ph[8 * sub + 3]);
        uint32_t H0 = cvtpk_bf16(ph[8 * sub + 4], ph[8 * sub + 5]);
        uint32_t H1 = cvtpk_bf16(ph[8 * sub + 6], ph[8 * sub + 7]);
        plswap32(L0, H0); plswap32(L1, H1);
        pa0[s].w[0] = L0; pa0[s].w[1] = L1; pa0[s].w[2] = H0; pa0[s].w[3] = H1;
      }
      {
        const f32x16 &ph = (s < 2) ? pA1 : pB1;
        uint32_t L0 = cvtpk_bf16(ph[8 * sub + 0], ph[8 * sub + 1]);
        uint32_t L1 = cvtpk_bf16(ph[8 * sub + 2], ph[8 * sub + 3]);
        uint32_t H0 = cvtpk_bf16(ph[8 * sub + 4], ph[8 * sub + 5]);
        uint32_t H1 = cvtpk_bf16(ph[8 * sub + 6], ph[8 * sub + 7]);
        plswap32(L0, H0); plswap32(L1, H1);
        pa1[s].w[0] = L0; pa1[s].w[1] = L1; pa1[s].w[2] = H0; pa1[s].w[3] = H1;
      }
    }

    // ---- PV: V-frags reused across both groups
    #pragma unroll
    for (int s = 0; s < 4; ++s) {
      const char* vbp = VtsB[cur] + (2 * s + hi) * 1040;
      s16x8 vlo = *(const s16x8*)(vbp + l31 * 16);
      s16x8 vhi = *(const s16x8*)(vbp + 512 + l31 * 16);
      oA0 = mfma32(pa0[s].v, vlo, oA0);
      oB0 = mfma32(pa0[s].v, vhi, oB0);
      oA1 = mfma32(pa1[s].v, vlo, oA1);
      oB1 = mfma32(pa1[s].v, vhi, oB1);
    }

    // ---- write-late; barrier drains lgkm only
    if (t < S_ / 64 - 1) WRITE(cur ^ 1);
    __syncthreads();
    cur ^= 1;
  }

  // ---- epilogue: combine partner l0, normalize, write (both groups)
  float l0t0 = l00 + __shfl_xor(l00, 32);
  float l0t1 = l01 + __shfl_xor(l01, 32);
  float inv0 = 1.0f / l0t0, inv1 = 1.0f / l0t1;   // lane's q = l31
  #pragma unroll
  for (int r = 0; r < 16; ++r) {
    int q = (r & 3) + 8 * (r >> 2) + 4 * hi;
    float ir0 = __shfl(inv0, q), ir1 = __shfl(inv1, q);
    int qrow = q0 + w * 64 + q;
    bf16* op0 = ob + (tokbase + qrow) * EMB + h * 64 + l31;
    op0[0]  = __float2bfloat16(oA0[r] * ir0);
    op0[32] = __float2bfloat16(oB0[r] * ir0);
    bf16* op1 = op0 + (size_t)32 * EMB;
    op1[0]  = __float2bfloat16(oA1[r] * ir1);
    op1[32] = __float2bfloat16(oB1[r] * ir1);
  }
}

// ---------------------------------------------------------------- launcher
// Workspace map (ob aliases xb — xb dead after gemm0, rewritten every replay):
//   [0,16MB) xb->ob  [16,22) wqkvb  [22,24) woutb  [24,72) qkvb  [72,88) vb
extern "C" void kernel_launch(void* const* d_in, const int* in_sizes, int n_in,
                              void* d_out, int out_size, void* d_ws, size_t ws_size,
                              hipStream_t stream) {
  const float* x    = (const float*)d_in[0];
  const float* Wqkv = (const float*)d_in[1];
  const float* bqkv = (const float*)d_in[2];
  const float* Wout = (const float*)d_in[3];
  const float* bout = (const float*)d_in[4];
  float* out = (float*)d_out;

  char* ws = (char*)d_ws;
  bf16* xb    = (bf16*)(ws);
  bf16* wqkvb = (bf16*)(ws + 16777216);
  bf16* woutb = (bf16*)(ws + 23068672);
  bf16* qkvb  = (bf16*)(ws + 25165824);
  bf16* vb    = (bf16*)(ws + 75497472);
  bf16* ob    = xb;

  cvt_all<<<dim3(6144), 256, 0, stream>>>(x, Wqkv, Wout, xb, wqkvb, woutb);

  gemm_bt<0><<<dim3(NQKV / 128, TOK / 128), 256, 0, stream>>>(
      xb, wqkvb, bqkv, qkvb, vb, nullptr, NQKV, DIN);

  attn2<<<dim3(256), 512, 0, stream>>>(qkvb, vb, ob);

  gemm_bt<1><<<dim3(EMB / 128, TOK / 128), 256, 0, stream>>>(
      ob, woutb, bout, nullptr, nullptr, out, EMB, EMB);
}